// Round 8
// baseline (223.004 us; speedup 1.0000x reference)
//
#include <hip/hip_runtime.h>
#include <hip/hip_bf16.h>
#include <stdint.h>

#define VOCAB 50257
#define WD 300
#define KP1 320              // word dim padded to mult of 32
#define MP 50432             // vocab rows padded: 394*128

using bf16 = __hip_bfloat16;
typedef __attribute__((ext_vector_type(4))) float f32x4;
typedef __attribute__((ext_vector_type(8))) short bf16x8;

// async global->LDS, 16B per lane; LDS dest = wave-uniform base + lane*16
__device__ __forceinline__ void async_load16(const void* g, void* l) {
    __builtin_amdgcn_global_load_lds(
        (const __attribute__((address_space(1))) uint32_t*)(uintptr_t)g,
        (__attribute__((address_space(3))) uint32_t*)l, 16, 0, 0);
}

// ---------- prep: w1t = W1^T bf16 [256x320]; w2t = W2^T bf16 [256x512];
//                  w2b = W2 cast bf16 [512x256]; b4 = b2@(A+B)+b2; zbuf zeros
__global__ void prep_w(const float* __restrict__ W1, const float* __restrict__ W2,
                       const float* __restrict__ b2,
                       bf16* __restrict__ w1t, bf16* __restrict__ w2t,
                       bf16* __restrict__ w2b, float* __restrict__ b4,
                       float* __restrict__ zbuf) {
    if (blockIdx.x == 1344) {           // bias block: b4 = b2@(A+B) + b2
        __shared__ float b2s[256];
        int n = threadIdx.x;
        b2s[n] = b2[n];
        zbuf[n] = 0.0f;
        __syncthreads();
        float acc = b2s[n];
        #pragma unroll 8
        for (int k = 0; k < 256; ++k)
            acc += b2s[k] * (W2[k * 256 + n] + W2[(k + 256) * 256 + n]);
        b4[n] = acc;
        return;
    }
    int idx = blockIdx.x * 256 + threadIdx.x;
    if (idx < 256 * KP1) {                              // w1t = W1^T (zero-pad)
        int n = idx / KP1;
        int k = idx - n * KP1;
        w1t[idx] = __float2bfloat16(k < WD ? W1[k * 256 + n] : 0.0f);
    } else if (idx < 256 * KP1 + 131072) {              // w2t = W2^T
        int j = idx - 256 * KP1;
        int n = j >> 9, k = j & 511;
        w2t[j] = __float2bfloat16(W2[k * 256 + n]);
    } else {                                            // w2b = cast(W2)
        int j = idx - 256 * KP1 - 131072;
        w2b[j] = __float2bfloat16(W2[j]);
    }
}

// ---------- unified 128-row x 256-col tile (8 waves: 2 rg x 4 cgr) -----------
// AMODE 0: A bf16, row stride As elems; 3-stage PIPE (verified)
// AMODE 2: A fp32 rows stride WD (emb, clamped); 2-stage PIPE w/ raw barriers
template <int AMODE, bool OUT_F32>
__device__ __forceinline__ void tile_gemm(
    char* smem, const void* Av, const int* ids,
    const bf16* BT, int Bstr, const float* bias,
    void* C, int Cs, int coff, int K, int As, int m0,
    const float* zbuf)
{
    constexpr int ASZ = (AMODE == 2) ? 16384 : 8192;
    constexpr int BSZ = 16384, STAGE = ASZ + BSZ;

    const int t = threadIdx.x, w = t >> 6, lane = t & 63;
    const int rg = w >> 2, cgr = w & 3, mi = lane & 15, q = lane >> 4;
    const bf16* Ab = (const bf16*)Av;

    auto stage = [&](int ke, int buf) {
        char* Asm = smem + buf * STAGE;
        char* Bsm = Asm + ASZ;
        if constexpr (AMODE == 2) {
            const float* A32 = (const float*)Av;
            #pragma unroll
            for (int i = 0; i < 2; ++i) {
                int s = i * 512 + t;
                int row = s >> 3;
                int kcd = (s & 7) ^ (row & 7);
                int k = ke + kcd * 4;
                int grow = m0 + row; if (grow >= VOCAB) grow = VOCAB - 1;
                const float* g = (k <= 296) ? (A32 + (size_t)grow * WD + k) : zbuf;
                async_load16(g, Asm + i * 8192 + w * 1024);
            }
        } else {
            int row = t >> 2;
            int kcd = (t & 3) ^ ((row >> 2) & 3);
            const bf16* g = Ab + (size_t)(m0 + row) * As + ke + kcd * 8;
            async_load16(g, Asm + w * 1024);
        }
        #pragma unroll
        for (int i = 0; i < 2; ++i) {
            int s = i * 512 + t;
            int col = s >> 2;
            int kcd = (s & 3) ^ ((col >> 2) & 3);
            async_load16(BT + (size_t)col * Bstr + ke + kcd * 8,
                         Bsm + i * 8192 + w * 1024);
        }
    };

    f32x4 acc[4][4] = {};

    auto compute = [&](int buf) {
        const char* Asm = smem + buf * STAGE;
        const bf16* Bs16 = (const bf16*)(Asm + ASZ);
        bf16x8 af[4], bfr[4];
        if constexpr (AMODE == 2) {
            const float* As32 = (const float*)Asm;
            #pragma unroll
            for (int r = 0; r < 4; ++r) {
                int row = rg * 64 + r * 16 + mi;
                int sl = row * 8 + ((2 * q) ^ (row & 7));
                f32x4 lo = *(const f32x4*)(As32 + sl * 4);
                f32x4 hi = *(const f32x4*)(As32 + (sl ^ 1) * 4);
                union { bf16x8 v; bf16 hh[8]; } u;
                #pragma unroll
                for (int j = 0; j < 4; ++j) u.hh[j] = __float2bfloat16(lo[j]);
                #pragma unroll
                for (int j = 0; j < 4; ++j) u.hh[4 + j] = __float2bfloat16(hi[j]);
                af[r] = u.v;
            }
        } else {
            const bf16* As16 = (const bf16*)Asm;
            #pragma unroll
            for (int r = 0; r < 4; ++r) {
                int row = rg * 64 + r * 16 + mi;
                int slot = row * 4 + (q ^ ((row >> 2) & 3));
                af[r] = *(const bf16x8*)(As16 + slot * 8);
            }
        }
        #pragma unroll
        for (int c = 0; c < 4; ++c) {
            int col = cgr * 64 + c * 16 + mi;
            int slot = col * 4 + (q ^ ((col >> 2) & 3));
            bfr[c] = *(const bf16x8*)(Bs16 + slot * 8);
        }
        #pragma unroll
        for (int r = 0; r < 4; ++r)
            #pragma unroll
            for (int c = 0; c < 4; ++c)
                acc[r][c] = __builtin_amdgcn_mfma_f32_16x16x32_bf16(af[r], bfr[c], acc[r][c], 0, 0, 0);
    };

    const int S = K >> 5;
    if constexpr (AMODE == 2) {
        stage(0, 0);
        for (int k0 = 0; k0 < S; ++k0) {
            if (k0 + 1 < S) {
                stage((k0 + 1) * 32, (k0 + 1) & 1);
                asm volatile("s_waitcnt vmcnt(4)\n\ts_barrier" ::: "memory");
            } else {
                asm volatile("s_waitcnt vmcnt(0)\n\ts_barrier" ::: "memory");
            }
            compute(k0 & 1);
            asm volatile("s_waitcnt lgkmcnt(0)\n\ts_barrier" ::: "memory");
        }
    } else {
        stage(0, 0);
        if (S > 1) stage(32, 1);
        for (int k0 = 0; k0 < S; ++k0) {
            if (k0 + 1 < S)
                asm volatile("s_waitcnt vmcnt(3)\n\ts_barrier" ::: "memory");
            else
                asm volatile("s_waitcnt vmcnt(0)\n\ts_barrier" ::: "memory");
            if (k0 + 2 < S) stage((k0 + 2) * 32, (k0 + 2) % 3);
            compute(k0 % 3);
        }
    }

    // epilogue: C/D layout col = lane&15, row = (lane>>4)*4 + i
    #pragma unroll
    for (int r = 0; r < 4; ++r) {
        int rowb = m0 + rg * 64 + r * 16 + q * 4;
        #pragma unroll
        for (int c = 0; c < 4; ++c) {
            int col = cgr * 64 + c * 16 + mi;
            float bv = bias[col];
            #pragma unroll
            for (int i = 0; i < 4; ++i) {
                float v = acc[r][c][i] + bv;
                size_t o = (size_t)(rowb + i) * Cs + coff + col;
                if (OUT_F32) ((float*)C)[o] = v;
                else         ((bf16*)C)[o] = __float2bfloat16(v);
            }
        }
    }
    (void)ids;
}

// ---------- D2: W4T (blocks 0..7) || proj (blocks 8..401) --------------------
__global__ __launch_bounds__(512)
void combo(const float* __restrict__ emb, const bf16* __restrict__ w1t,
           const float* __restrict__ b1, const bf16* __restrict__ w2t,
           const bf16* __restrict__ w2b, bf16* __restrict__ w4t,
           bf16* __restrict__ proj, const float* __restrict__ zbuf) {
    __shared__ char smem[73728];
    int blk = blockIdx.x;
    if (blk < 8) {
        int j = blk >> 1, s = blk & 1;
        tile_gemm<0, false>(smem, w2t + 256 * (j >> 1), nullptr,
                            w2b + 65536 * (j & 1), 256, zbuf,
                            w4t, 1024, 256 * j, 256, 512, s * 128, nullptr);
    } else {
        tile_gemm<2, false>(smem, emb, nullptr, w1t, KP1, b1,
                            proj, 256, 0, KP1, WD, (blk - 8) * 128, zbuf);
    }
}

// ---------- D3: w4cK — coalesced-B permutation of w4t (R6-verified) ----------
// unit u (16B) = (cg*32+ks)*64 + lane; holds w4t[cg*16+mi][ks*32+q*8 .. +7]
__global__ __launch_bounds__(512)
void w4cK(const bf16* __restrict__ w4t, bf16* __restrict__ w4c) {
    const int tid = blockIdx.x * 512 + threadIdx.x;      // 8 blocks = 4096 thr
    #pragma unroll
    for (int i = 0; i < 8; ++i) {
        int u = i * 4096 + tid;                          // 32768 units total
        int ln = u & 63, ks = (u >> 6) & 31, cg = u >> 11;
        int mi2 = ln & 15, q2 = ln >> 4;
        *(int4*)(w4c + (size_t)u * 8) =
            *(const int4*)(w4t + (size_t)(cg * 16 + mi2) * 1024 + ks * 32 + q2 * 8);
    }
}

// ---------- D4: mainK — h = concat4(proj[ids4]) @ W4 + b4 --------------------
// Grid 1024 = 512 rowtiles x 2 col-halves; block = 128 rows x 128 cols.
// Wave w owns cols c0 + w*16..+15 (cg = ch*8+w) -> acc[8]+af[8]+bp[2] ~90 VGPR,
// no occupancy cap, no spills. A (gathered proj rows) through a 4-deep LDS
// ring, 1 DMA/thread/round; B DIRECT from w4c (coalesced, prefetch-1,
// compiler-tracked). One fence/round: vmcnt(2) lgkmcnt(0); s_barrier.
// vmcnt(2) is spill-robust: the DMA needing drain (stageA(r)) always has
// >=4 vmcnt ops issued after it; spills only add more. Last round vmcnt(0).
__global__ __launch_bounds__(512)
void mainK(const bf16* __restrict__ proj, const int* __restrict__ ids,
           const bf16* __restrict__ w4c, const float* __restrict__ b4,
           bf16* __restrict__ h) {
    __shared__ char Abuf[4][8192];
    const int t = threadIdx.x, w = t >> 6, lane = t & 63;
    const int mi = lane & 15, q = lane >> 4;
    const int rt = blockIdx.x >> 1, ch = blockIdx.x & 1;
    const int m0 = rt * 128;
    const int c0 = ch * 128;
    const int cg = ch * 8 + w;

    const int4 idq = ((const int4*)ids)[m0 + (t >> 2)];

    auto stageA = [&](int r, int buf) {
        int ke = r * 32;
        int row = t >> 2;
        int kcd = (t & 3) ^ ((row >> 2) & 3);
        int sel = ke >> 8;
        int id = (sel & 2) ? ((sel & 1) ? idq.w : idq.z)
                           : ((sel & 1) ? idq.y : idq.x);
        async_load16(proj + (size_t)id * 256 + (ke & 255) + kcd * 8,
                     Abuf[buf] + w * 1024);
        (void)row;
    };

    f32x4 acc[8] = {};
    bf16x8 bp[2];

    stageA(0, 0); stageA(1, 1);
    bp[0] = *(const bf16x8*)(w4c + ((size_t)(cg * 32 + 0) * 64 + lane) * 8);

    #pragma unroll
    for (int r = 0; r < 32; ++r) {
        if (r + 2 < 32) stageA(r + 2, (r + 2) & 3);
        if (r + 1 < 32)
            bp[(r + 1) & 1] = *(const bf16x8*)(
                w4c + ((size_t)(cg * 32 + (r + 1)) * 64 + lane) * 8);
        if (r + 1 < 32)
            asm volatile("s_waitcnt vmcnt(2) lgkmcnt(0)\n\ts_barrier" ::: "memory");
        else
            asm volatile("s_waitcnt vmcnt(0) lgkmcnt(0)\n\ts_barrier" ::: "memory");
        const bf16* As16 = (const bf16*)Abuf[r & 3];
        #pragma unroll
        for (int ri = 0; ri < 8; ++ri) {
            int row = ri * 16 + mi;
            int slot = row * 4 + (q ^ ((row >> 2) & 3));
            bf16x8 af = *(const bf16x8*)(As16 + slot * 8);
            acc[ri] = __builtin_amdgcn_mfma_f32_16x16x32_bf16(af, bp[r & 1], acc[ri], 0, 0, 0);
        }
    }

    const int col = c0 + w * 16 + mi;
    const float bv = b4[col];
    #pragma unroll
    for (int ri = 0; ri < 8; ++ri) {
        int rowb = m0 + ri * 16 + q * 4;
        #pragma unroll
        for (int i = 0; i < 4; ++i)
            h[(size_t)(rowb + i) * 256 + col] = __float2bfloat16(acc[ri][i] + bv);
    }
}

// ---------- D5: treeK — levels 2-10 block-local (256 blocks, all CUs) --------
// R6-VERIFIED VERBATIM. Phase A: 64x256, K=1024, 16 fat rounds, 2-stage pipe
// (A+B staged via w4t). Phases B/C/D: B coalesced from w4c, barrier-free.
__global__ __launch_bounds__(512)
void treeK(const bf16* __restrict__ h, const bf16* __restrict__ w4t,
           const bf16* __restrict__ w4c, const float* __restrict__ b4,
           float* __restrict__ out) {
    constexpr int ASZ = 8192, BSZ = 32768, STAGE = ASZ + BSZ;
    __shared__ char smem[2 * STAGE];   // 80 KB pipe
    __shared__ bf16 Ht[64 * 256];      // 32 KB
    __shared__ bf16 Ht2[16 * 256];     // 8 KB
    __shared__ bf16 Ht3[4 * 256];      // 2 KB  (total 122 KB)

    const int t = threadIdx.x, w = t >> 6, lane = t & 63;
    const int mi = lane & 15, q = lane >> 4;
    const int b = blockIdx.x;

    // ---- phase A: 64x256 tile, K=1024, 16 rounds x 64k -> Ht ----
    {
        auto stage = [&](int r, int buf) {
            char* As = smem + buf * STAGE;
            char* Bs = As + ASZ;
            const int kb = r * 64;
            {   // A: 64 rows x 64k; row=t>>3, chunk c=t&7 stored at c^(row&7)
                int row = t >> 3, c = t & 7;
                async_load16(h + (size_t)(64 * b + row) * 1024 + kb + ((c ^ (row & 7)) << 3),
                             As + w * 1024);
            }
            #pragma unroll
            for (int sub = 0; sub < 2; ++sub)       // B: 256 cols x 64k
                #pragma unroll
                for (int i = 0; i < 2; ++i) {
                    int s = i * 512 + t;
                    int col = s >> 2;
                    int kcd = (s & 3) ^ ((col >> 2) & 3);
                    async_load16(w4t + (size_t)col * 1024 + kb + sub * 32 + kcd * 8,
                                 Bs + sub * 16384 + i * 8192 + w * 1024);
                }
        };
        f32x4 acc[4][2] = {};
        stage(0, 0);
        for (int r = 0; r < 16; ++r) {
            if (r + 1 < 16) {
                stage(r + 1, (r + 1) & 1);
                asm volatile("s_waitcnt vmcnt(5)\n\ts_barrier" ::: "memory");
            } else {
                asm volatile("s_waitcnt vmcnt(0)\n\ts_barrier" ::: "memory");
            }
            const bf16* As16 = (const bf16*)(smem + (r & 1) * STAGE);
            const bf16* Bb   = (const bf16*)(smem + (r & 1) * STAGE + ASZ);
            #pragma unroll
            for (int kk = 0; kk < 2; ++kk) {
                bf16x8 af[4], bfr[2];
                #pragma unroll
                for (int ri = 0; ri < 4; ++ri) {
                    int row = ri * 16 + mi;
                    int c = kk * 4 + q;
                    af[ri] = *(const bf16x8*)(As16 + (row * 8 + (c ^ (row & 7))) * 8);
                }
                #pragma unroll
                for (int c4 = 0; c4 < 2; ++c4) {
                    int col = w * 32 + c4 * 16 + mi;
                    int slot = col * 4 + (q ^ ((col >> 2) & 3));
                    bfr[c4] = *(const bf16x8*)(Bb + kk * 8192 + slot * 8);
                }
                #pragma unroll
                for (int ri = 0; ri < 4; ++ri)
                    #pragma unroll
                    for (int c4 = 0; c4 < 2; ++c4)
                        acc[ri][c4] = __builtin_amdgcn_mfma_f32_16x16x32_bf16(af[ri], bfr[c4], acc[ri][c4], 0, 0, 0);
            }
            asm volatile("s_waitcnt lgkmcnt(0)\n\ts_barrier" ::: "memory");
        }
        // epilogue -> Ht (XOR-swizzled, matches phase-B read formula)
        #pragma unroll
        for (int ri = 0; ri < 4; ++ri) {
            #pragma unroll
            for (int c4 = 0; c4 < 2; ++c4) {
                int col = w * 32 + c4 * 16 + mi;
                float bv = b4[col];
                int chunk = col >> 3;
                #pragma unroll
                for (int i = 0; i < 4; ++i) {
                    int row = ri * 16 + q * 4 + i;
                    Ht[(row * 32 + (chunk ^ (row & 31))) * 8 + (col & 7)] =
                        __float2bfloat16(acc[ri][c4][i] + bv);
                }
            }
        }
    }
    __syncthreads();

    // ---- phase B: 16 rows -> Ht2 (B coalesced from w4c) ----
    {
        f32x4 acc[2] = {};
        #pragma unroll 8
        for (int ks = 0; ks < 32; ++ks) {
            int kc = (ks & 7) * 4 + q;
            int r2 = 4 * mi + (ks >> 3);
            bf16x8 a = *(const bf16x8*)(Ht + (r2 * 32 + (kc ^ (r2 & 31))) * 8);
            #pragma unroll
            for (int g = 0; g < 2; ++g) {
                bf16x8 bb = *(const bf16x8*)(w4c + ((size_t)((2 * w + g) * 32 + ks) * 64 + lane) * 8);
                acc[g] = __builtin_amdgcn_mfma_f32_16x16x32_bf16(a, bb, acc[g], 0, 0, 0);
            }
        }
        #pragma unroll
        for (int g = 0; g < 2; ++g) {
            int col = w * 32 + g * 16 + mi;
            float bv = b4[col];
            int chunk = col >> 3;
            #pragma unroll
            for (int i = 0; i < 4; ++i) {
                int row = q * 4 + i;
                Ht2[(row * 32 + (chunk ^ (row & 15))) * 8 + (col & 7)] =
                    __float2bfloat16(acc[g][i] + bv);
            }
        }
    }
    __syncthreads();

    // ---- phase C: 4 rows -> Ht3 (B coalesced from w4c) ----
    {
        f32x4 acc[2] = {};
        #pragma unroll 8
        for (int ks = 0; ks < 32; ++ks) {
            int kc = (ks & 7) * 4 + q;
            int r3 = (4 * mi + (ks >> 3)) & 15;
            bf16x8 a = *(const bf16x8*)(Ht2 + (r3 * 32 + (kc ^ (r3 & 15))) * 8);
            #pragma unroll
            for (int g = 0; g < 2; ++g) {
                bf16x8 bb = *(const bf16x8*)(w4c + ((size_t)((2 * w + g) * 32 + ks) * 64 + lane) * 8);
                acc[g] = __builtin_amdgcn_mfma_f32_16x16x32_bf16(a, bb, acc[g], 0, 0, 0);
            }
        }
        if (q == 0) {
            #pragma unroll
            for (int g = 0; g < 2; ++g) {
                int col = w * 32 + g * 16 + mi;
                float bv = b4[col];
                #pragma unroll
                for (int i = 0; i < 4; ++i)
                    Ht3[i * 256 + col] = __float2bfloat16(acc[g][i] + bv);
            }
        }
    }
    __syncthreads();

    // ---- phase D: 1 root -> out (B coalesced from w4c) ----
    {
        f32x4 acc[2] = {};
        #pragma unroll 8
        for (int ks = 0; ks < 32; ++ks) {
            int r4 = (4 * mi + (ks >> 3)) & 3;
            bf16x8 a = *(const bf16x8*)(Ht3 + r4 * 256 + (ks & 7) * 32 + q * 8);
            #pragma unroll
            for (int g = 0; g < 2; ++g) {
                bf16x8 bb = *(const bf16x8*)(w4c + ((size_t)((2 * w + g) * 32 + ks) * 64 + lane) * 8);
                acc[g] = __builtin_amdgcn_mfma_f32_16x16x32_bf16(a, bb, acc[g], 0, 0, 0);
            }
        }
        if (q == 0) {
            #pragma unroll
            for (int g = 0; g < 2; ++g) {
                int col = w * 32 + g * 16 + mi;
                out[(size_t)b * 256 + col] = acc[g][0] + b4[col];
            }
        }
    }
}

extern "C" void kernel_launch(void* const* d_in, const int* in_sizes, int n_in,
                              void* d_out, int out_size, void* d_ws, size_t ws_size,
                              hipStream_t stream) {
    const int*   ids = (const int*)d_in[0];
    const float* emb = (const float*)d_in[1];
    const float* W1  = (const float*)d_in[2];
    const float* b1  = (const float*)d_in[3];
    const float* W2  = (const float*)d_in[4];
    const float* b2  = (const float*)d_in[5];
    (void)in_sizes; (void)n_in; (void)out_size; (void)ws_size;

    char* ws = (char*)d_ws;
    size_t off = 0;
    float* zbuf = (float*)(ws + off); off += 1024;
    float* b4   = (float*)(ws + off); off += 1024;
    bf16* w1t = (bf16*)(ws + off); off += (size_t)256 * KP1 * 2;     // 160 KB
    bf16* w2t = (bf16*)(ws + off); off += (size_t)256 * 512 * 2;     // 256 KB
    bf16* w2b = (bf16*)(ws + off); off += (size_t)512 * 256 * 2;     // 256 KB
    bf16* w4t = (bf16*)(ws + off); off += (size_t)256 * 1024 * 2;    // 512 KB
    bf16* w4c = (bf16*)(ws + off); off += (size_t)256 * 1024 * 2;    // 512 KB
    bf16* proj = (bf16*)(ws + off); off += (size_t)MP * 256 * 2;     // 25.8 MB
    bf16* h  = (bf16*)(ws + off); off += (size_t)65536 * 256 * 2;    // 33.5 MB
    (void)off;

    // D1: weight casts/transposes + b4 + zeros
    prep_w<<<1345, 256, 0, stream>>>(W1, W2, b2, w1t, w2t, w2b, b4, zbuf);

    // D2: W4T (blocks 0..7) || proj (blocks 8..401)
    combo<<<402, 512, 0, stream>>>(emb, w1t, b1, w2t, w2b, w4t, proj, zbuf);

    // D3: coalesced-B permutation (tiny; feeds mainK + treeK phases B-D)
    w4cK<<<8, 512, 0, stream>>>(w4t, w4c);

    // D4: main — leaves + levels 0-1 (A-ring + w4c register-B, robust vmcnt)
    mainK<<<1024, 512, 0, stream>>>(proj, ids, w4c, b4, h);

    // D5: levels 2-10 block-local, 256 blocks (R6-verified)
    treeK<<<256, 512, 0, stream>>>(h, w4t, w4c, b4, (float*)d_out);
}

// Round 10
// 213.276 us; speedup vs baseline: 1.0456x; 1.0456x over previous
//
#include <hip/hip_runtime.h>
#include <hip/hip_bf16.h>
#include <stdint.h>

#define VOCAB 50257
#define WD 300
#define KP1 320              // word dim padded to mult of 32
#define MP 50432             // vocab rows padded: 394*128

using bf16 = __hip_bfloat16;
typedef __attribute__((ext_vector_type(4))) float f32x4;
typedef __attribute__((ext_vector_type(8))) short bf16x8;

// async global->LDS, 16B per lane; LDS dest = wave-uniform base + lane*16
__device__ __forceinline__ void async_load16(const void* g, void* l) {
    __builtin_amdgcn_global_load_lds(
        (const __attribute__((address_space(1))) uint32_t*)(uintptr_t)g,
        (__attribute__((address_space(3))) uint32_t*)l, 16, 0, 0);
}

// ---------- prep: w1t = W1^T bf16 [256x320]; w2t = W2^T bf16 [256x512];
//                  w2b = W2 cast bf16 [512x256]; b4 = b2@(A+B)+b2; zbuf zeros
__global__ void prep_w(const float* __restrict__ W1, const float* __restrict__ W2,
                       const float* __restrict__ b2,
                       bf16* __restrict__ w1t, bf16* __restrict__ w2t,
                       bf16* __restrict__ w2b, float* __restrict__ b4,
                       float* __restrict__ zbuf) {
    if (blockIdx.x == 1344) {           // bias block: b4 = b2@(A+B) + b2
        __shared__ float b2s[256];
        int n = threadIdx.x;
        b2s[n] = b2[n];
        zbuf[n] = 0.0f;
        __syncthreads();
        float acc = b2s[n];
        #pragma unroll 8
        for (int k = 0; k < 256; ++k)
            acc += b2s[k] * (W2[k * 256 + n] + W2[(k + 256) * 256 + n]);
        b4[n] = acc;
        return;
    }
    int idx = blockIdx.x * 256 + threadIdx.x;
    if (idx < 256 * KP1) {                              // w1t = W1^T (zero-pad)
        int n = idx / KP1;
        int k = idx - n * KP1;
        w1t[idx] = __float2bfloat16(k < WD ? W1[k * 256 + n] : 0.0f);
    } else if (idx < 256 * KP1 + 131072) {              // w2t = W2^T
        int j = idx - 256 * KP1;
        int n = j >> 9, k = j & 511;
        w2t[j] = __float2bfloat16(W2[k * 256 + n]);
    } else {                                            // w2b = cast(W2)
        int j = idx - 256 * KP1 - 131072;
        w2b[j] = __float2bfloat16(W2[j]);
    }
}

// ---------- unified 128-row x 256-col tile (8 waves: 2 rg x 4 cgr) -----------
// AMODE 0: A bf16, row stride As elems; 3-stage PIPE (verified)
// AMODE 2: A fp32 rows stride WD (emb, clamped); 2-stage PIPE w/ raw barriers
template <int AMODE, bool OUT_F32>
__device__ __forceinline__ void tile_gemm(
    char* smem, const void* Av, const int* ids,
    const bf16* BT, int Bstr, const float* bias,
    void* C, int Cs, int coff, int K, int As, int m0,
    const float* zbuf)
{
    constexpr int ASZ = (AMODE == 2) ? 16384 : 8192;
    constexpr int BSZ = 16384, STAGE = ASZ + BSZ;

    const int t = threadIdx.x, w = t >> 6, lane = t & 63;
    const int rg = w >> 2, cgr = w & 3, mi = lane & 15, q = lane >> 4;
    const bf16* Ab = (const bf16*)Av;

    auto stage = [&](int ke, int buf) {
        char* Asm = smem + buf * STAGE;
        char* Bsm = Asm + ASZ;
        if constexpr (AMODE == 2) {
            const float* A32 = (const float*)Av;
            #pragma unroll
            for (int i = 0; i < 2; ++i) {
                int s = i * 512 + t;
                int row = s >> 3;
                int kcd = (s & 7) ^ (row & 7);
                int k = ke + kcd * 4;
                int grow = m0 + row; if (grow >= VOCAB) grow = VOCAB - 1;
                const float* g = (k <= 296) ? (A32 + (size_t)grow * WD + k) : zbuf;
                async_load16(g, Asm + i * 8192 + w * 1024);
            }
        } else {
            int row = t >> 2;
            int kcd = (t & 3) ^ ((row >> 2) & 3);
            const bf16* g = Ab + (size_t)(m0 + row) * As + ke + kcd * 8;
            async_load16(g, Asm + w * 1024);
        }
        #pragma unroll
        for (int i = 0; i < 2; ++i) {
            int s = i * 512 + t;
            int col = s >> 2;
            int kcd = (s & 3) ^ ((col >> 2) & 3);
            async_load16(BT + (size_t)col * Bstr + ke + kcd * 8,
                         Bsm + i * 8192 + w * 1024);
        }
    };

    f32x4 acc[4][4] = {};

    auto compute = [&](int buf) {
        const char* Asm = smem + buf * STAGE;
        const bf16* Bs16 = (const bf16*)(Asm + ASZ);
        bf16x8 af[4], bfr[4];
        if constexpr (AMODE == 2) {
            const float* As32 = (const float*)Asm;
            #pragma unroll
            for (int r = 0; r < 4; ++r) {
                int row = rg * 64 + r * 16 + mi;
                int sl = row * 8 + ((2 * q) ^ (row & 7));
                f32x4 lo = *(const f32x4*)(As32 + sl * 4);
                f32x4 hi = *(const f32x4*)(As32 + (sl ^ 1) * 4);
                union { bf16x8 v; bf16 hh[8]; } u;
                #pragma unroll
                for (int j = 0; j < 4; ++j) u.hh[j] = __float2bfloat16(lo[j]);
                #pragma unroll
                for (int j = 0; j < 4; ++j) u.hh[4 + j] = __float2bfloat16(hi[j]);
                af[r] = u.v;
            }
        } else {
            const bf16* As16 = (const bf16*)Asm;
            #pragma unroll
            for (int r = 0; r < 4; ++r) {
                int row = rg * 64 + r * 16 + mi;
                int slot = row * 4 + (q ^ ((row >> 2) & 3));
                af[r] = *(const bf16x8*)(As16 + slot * 8);
            }
        }
        #pragma unroll
        for (int c = 0; c < 4; ++c) {
            int col = cgr * 64 + c * 16 + mi;
            int slot = col * 4 + (q ^ ((col >> 2) & 3));
            bfr[c] = *(const bf16x8*)(Bs16 + slot * 8);
        }
        #pragma unroll
        for (int r = 0; r < 4; ++r)
            #pragma unroll
            for (int c = 0; c < 4; ++c)
                acc[r][c] = __builtin_amdgcn_mfma_f32_16x16x32_bf16(af[r], bfr[c], acc[r][c], 0, 0, 0);
    };

    const int S = K >> 5;
    if constexpr (AMODE == 2) {
        stage(0, 0);
        for (int k0 = 0; k0 < S; ++k0) {
            if (k0 + 1 < S) {
                stage((k0 + 1) * 32, (k0 + 1) & 1);
                asm volatile("s_waitcnt vmcnt(4)\n\ts_barrier" ::: "memory");
            } else {
                asm volatile("s_waitcnt vmcnt(0)\n\ts_barrier" ::: "memory");
            }
            compute(k0 & 1);
            asm volatile("s_waitcnt lgkmcnt(0)\n\ts_barrier" ::: "memory");
        }
    } else {
        stage(0, 0);
        if (S > 1) stage(32, 1);
        for (int k0 = 0; k0 < S; ++k0) {
            if (k0 + 1 < S)
                asm volatile("s_waitcnt vmcnt(3)\n\ts_barrier" ::: "memory");
            else
                asm volatile("s_waitcnt vmcnt(0)\n\ts_barrier" ::: "memory");
            if (k0 + 2 < S) stage((k0 + 2) * 32, (k0 + 2) % 3);
            compute(k0 % 3);
        }
    }

    // epilogue: C/D layout col = lane&15, row = (lane>>4)*4 + i
    #pragma unroll
    for (int r = 0; r < 4; ++r) {
        int rowb = m0 + rg * 64 + r * 16 + q * 4;
        #pragma unroll
        for (int c = 0; c < 4; ++c) {
            int col = cgr * 64 + c * 16 + mi;
            float bv = bias[col];
            #pragma unroll
            for (int i = 0; i < 4; ++i) {
                float v = acc[r][c][i] + bv;
                size_t o = (size_t)(rowb + i) * Cs + coff + col;
                if (OUT_F32) ((float*)C)[o] = v;
                else         ((bf16*)C)[o] = __float2bfloat16(v);
            }
        }
    }
    (void)ids;
}

// ---------- D2: W4T (blocks 0..7) || proj (blocks 8..401) --------------------
__global__ __launch_bounds__(512)
void combo(const float* __restrict__ emb, const bf16* __restrict__ w1t,
           const float* __restrict__ b1, const bf16* __restrict__ w2t,
           const bf16* __restrict__ w2b, bf16* __restrict__ w4t,
           bf16* __restrict__ proj, const float* __restrict__ zbuf) {
    __shared__ char smem[73728];
    int blk = blockIdx.x;
    if (blk < 8) {
        int j = blk >> 1, s = blk & 1;
        tile_gemm<0, false>(smem, w2t + 256 * (j >> 1), nullptr,
                            w2b + 65536 * (j & 1), 256, zbuf,
                            w4t, 1024, 256 * j, 256, 512, s * 128, nullptr);
    } else {
        tile_gemm<2, false>(smem, emb, nullptr, w1t, KP1, b1,
                            proj, 256, 0, KP1, WD, (blk - 8) * 128, zbuf);
    }
}

// ---------- D3: w4cK — coalesced-B permutation of w4t (R6-verified) ----------
// unit u (16B) = (cg*32+ks)*64 + lane; holds w4t[cg*16+mi][ks*32+q*8 .. +7]
__global__ __launch_bounds__(512)
void w4cK(const bf16* __restrict__ w4t, bf16* __restrict__ w4c) {
    const int tid = blockIdx.x * 512 + threadIdx.x;      // 8 blocks = 4096 thr
    #pragma unroll
    for (int i = 0; i < 8; ++i) {
        int u = i * 4096 + tid;                          // 32768 units total
        int ln = u & 63, ks = (u >> 6) & 31, cg = u >> 11;
        int mi2 = ln & 15, q2 = ln >> 4;
        *(int4*)(w4c + (size_t)u * 8) =
            *(const int4*)(w4t + (size_t)(cg * 16 + mi2) * 1024 + ks * 32 + q2 * 8);
    }
}

// ---------- D4: mainK — h = concat4(proj[ids4]) @ W4 + b4 --------------------
// 512 blocks x (128 rows x 256 cols), R6 wave tiling (2 rg x 4 cgr, 16 MFMA/
// wave/round). A via 4-deep LDS ring (1 DMA/thread/round). B DIRECT from w4c
// to registers bp0/bp1 (coalesced 1KB/wave/frag, prefetch-1); loop manually
// unrolled x2 so all bp[] indices are compile-time (rule 20).
// Fence math (target = stageA(r), drained by compute r): explicit VMEM ops
// issued after it = stageA(r+1) + loadB(r)x4 + stageA(r+2) + loadB(r+1)x4
// = 10 -> vmcnt(10) drains exactly stageA(r), keeps a full round of prefetch
// in flight, and is SPILL-ROBUST (spills only add newer ops). Tail: r=30 ->
// vmcnt(9), r=31 -> vmcnt(0). lgkmcnt(0) drains ds_reads for ring reuse.
__global__ __launch_bounds__(512)
void mainK(const bf16* __restrict__ proj, const int* __restrict__ ids,
           const bf16* __restrict__ w4c, const float* __restrict__ b4,
           bf16* __restrict__ h) {
    __shared__ char Abuf[4][8192];
    const int t = threadIdx.x, w = t >> 6, lane = t & 63;
    const int rg = w >> 2, cgr = w & 3, mi = lane & 15, q = lane >> 4;
    const int m0 = blockIdx.x * 128;

    const int4 idq = ((const int4*)ids)[m0 + (t >> 2)];

    auto stageA = [&](int r, int buf) {
        int ke = r * 32;
        int kcd = (t & 3) ^ (((t >> 2) >> 2) & 3);
        int sel = ke >> 8;
        int id = (sel & 2) ? ((sel & 1) ? idq.w : idq.z)
                           : ((sel & 1) ? idq.y : idq.x);
        async_load16(proj + (size_t)id * 256 + (ke & 255) + kcd * 8,
                     Abuf[buf] + w * 1024);
    };

    f32x4 acc[4][4] = {};
    bf16x8 bp0[4], bp1[4];

    auto loadB0 = [&](int r) {
        #pragma unroll
        for (int c = 0; c < 4; ++c)
            bp0[c] = *(const bf16x8*)(
                w4c + ((size_t)((cgr * 4 + c) * 32 + r) * 64 + lane) * 8);
    };
    auto loadB1 = [&](int r) {
        #pragma unroll
        for (int c = 0; c < 4; ++c)
            bp1[c] = *(const bf16x8*)(
                w4c + ((size_t)((cgr * 4 + c) * 32 + r) * 64 + lane) * 8);
    };

    auto doMfma = [&](const bf16* As16, const bf16x8* bp) {
        bf16x8 af[4];
        #pragma unroll
        for (int ri = 0; ri < 4; ++ri) {
            int row = rg * 64 + ri * 16 + mi;
            int slot = row * 4 + (q ^ ((row >> 2) & 3));
            af[ri] = *(const bf16x8*)(As16 + slot * 8);
        }
        #pragma unroll
        for (int ri = 0; ri < 4; ++ri)
            #pragma unroll
            for (int c = 0; c < 4; ++c)
                acc[ri][c] = __builtin_amdgcn_mfma_f32_16x16x32_bf16(
                    af[ri], bp[c], acc[ri][c], 0, 0, 0);
    };

    stageA(0, 0); stageA(1, 1);
    loadB0(0);

    // rounds 0..29 (pairs): steady fence vmcnt(10)
    for (int rr = 0; rr < 30; rr += 2) {
        // even round r = rr: compute uses bp0, prefetch into bp1
        stageA(rr + 2, (rr + 2) & 3);
        loadB1(rr + 1);
        asm volatile("s_waitcnt vmcnt(10) lgkmcnt(0)\n\ts_barrier" ::: "memory");
        doMfma((const bf16*)Abuf[rr & 3], bp0);
        // odd round r = rr+1: compute uses bp1, prefetch into bp0
        stageA(rr + 3, (rr + 3) & 3);
        loadB0(rr + 2);
        asm volatile("s_waitcnt vmcnt(10) lgkmcnt(0)\n\ts_barrier" ::: "memory");
        doMfma((const bf16*)Abuf[(rr + 1) & 3], bp1);
    }
    // round 30: no stageA(32); loadB into bp1 for round 31
    loadB1(31);
    asm volatile("s_waitcnt vmcnt(9) lgkmcnt(0)\n\ts_barrier" ::: "memory");
    doMfma((const bf16*)Abuf[30 & 3], bp0);
    // round 31: final
    asm volatile("s_waitcnt vmcnt(0) lgkmcnt(0)\n\ts_barrier" ::: "memory");
    doMfma((const bf16*)Abuf[31 & 3], bp1);

    #pragma unroll
    for (int ri = 0; ri < 4; ++ri) {
        int rowb = m0 + rg * 64 + ri * 16 + q * 4;
        #pragma unroll
        for (int c = 0; c < 4; ++c) {
            int col = cgr * 64 + c * 16 + mi;
            float bv = b4[col];
            #pragma unroll
            for (int i = 0; i < 4; ++i)
                h[(size_t)(rowb + i) * 256 + col] = __float2bfloat16(acc[ri][c][i] + bv);
        }
    }
}

// ---------- D5: treeK — levels 2-10 block-local (256 blocks, all CUs) --------
// R6-VERIFIED VERBATIM. Phase A: 64x256, K=1024, 16 fat rounds, 2-stage pipe
// (A+B staged via w4t). Phases B/C/D: B coalesced from w4c, barrier-free.
__global__ __launch_bounds__(512)
void treeK(const bf16* __restrict__ h, const bf16* __restrict__ w4t,
           const bf16* __restrict__ w4c, const float* __restrict__ b4,
           float* __restrict__ out) {
    constexpr int ASZ = 8192, BSZ = 32768, STAGE = ASZ + BSZ;
    __shared__ char smem[2 * STAGE];   // 80 KB pipe
    __shared__ bf16 Ht[64 * 256];      // 32 KB
    __shared__ bf16 Ht2[16 * 256];     // 8 KB
    __shared__ bf16 Ht3[4 * 256];      // 2 KB  (total 122 KB)

    const int t = threadIdx.x, w = t >> 6, lane = t & 63;
    const int mi = lane & 15, q = lane >> 4;
    const int b = blockIdx.x;

    // ---- phase A: 64x256 tile, K=1024, 16 rounds x 64k -> Ht ----
    {
        auto stage = [&](int r, int buf) {
            char* As = smem + buf * STAGE;
            char* Bs = As + ASZ;
            const int kb = r * 64;
            {   // A: 64 rows x 64k; row=t>>3, chunk c=t&7 stored at c^(row&7)
                int row = t >> 3, c = t & 7;
                async_load16(h + (size_t)(64 * b + row) * 1024 + kb + ((c ^ (row & 7)) << 3),
                             As + w * 1024);
            }
            #pragma unroll
            for (int sub = 0; sub < 2; ++sub)       // B: 256 cols x 64k
                #pragma unroll
                for (int i = 0; i < 2; ++i) {
                    int s = i * 512 + t;
                    int col = s >> 2;
                    int kcd = (s & 3) ^ ((col >> 2) & 3);
                    async_load16(w4t + (size_t)col * 1024 + kb + sub * 32 + kcd * 8,
                                 Bs + sub * 16384 + i * 8192 + w * 1024);
                }
        };
        f32x4 acc[4][2] = {};
        stage(0, 0);
        for (int r = 0; r < 16; ++r) {
            if (r + 1 < 16) {
                stage(r + 1, (r + 1) & 1);
                asm volatile("s_waitcnt vmcnt(5)\n\ts_barrier" ::: "memory");
            } else {
                asm volatile("s_waitcnt vmcnt(0)\n\ts_barrier" ::: "memory");
            }
            const bf16* As16 = (const bf16*)(smem + (r & 1) * STAGE);
            const bf16* Bb   = (const bf16*)(smem + (r & 1) * STAGE + ASZ);
            #pragma unroll
            for (int kk = 0; kk < 2; ++kk) {
                bf16x8 af[4], bfr[2];
                #pragma unroll
                for (int ri = 0; ri < 4; ++ri) {
                    int row = ri * 16 + mi;
                    int c = kk * 4 + q;
                    af[ri] = *(const bf16x8*)(As16 + (row * 8 + (c ^ (row & 7))) * 8);
                }
                #pragma unroll
                for (int c4 = 0; c4 < 2; ++c4) {
                    int col = w * 32 + c4 * 16 + mi;
                    int slot = col * 4 + (q ^ ((col >> 2) & 3));
                    bfr[c4] = *(const bf16x8*)(Bb + kk * 8192 + slot * 8);
                }
                #pragma unroll
                for (int ri = 0; ri < 4; ++ri)
                    #pragma unroll
                    for (int c4 = 0; c4 < 2; ++c4)
                        acc[ri][c4] = __builtin_amdgcn_mfma_f32_16x16x32_bf16(af[ri], bfr[c4], acc[ri][c4], 0, 0, 0);
            }
            asm volatile("s_waitcnt lgkmcnt(0)\n\ts_barrier" ::: "memory");
        }
        // epilogue -> Ht (XOR-swizzled, matches phase-B read formula)
        #pragma unroll
        for (int ri = 0; ri < 4; ++ri) {
            #pragma unroll
            for (int c4 = 0; c4 < 2; ++c4) {
                int col = w * 32 + c4 * 16 + mi;
                float bv = b4[col];
                int chunk = col >> 3;
                #pragma unroll
                for (int i = 0; i < 4; ++i) {
                    int row = ri * 16 + q * 4 + i;
                    Ht[(row * 32 + (chunk ^ (row & 31))) * 8 + (col & 7)] =
                        __float2bfloat16(acc[ri][c4][i] + bv);
                }
            }
        }
    }
    __syncthreads();

    // ---- phase B: 16 rows -> Ht2 (B coalesced from w4c) ----
    {
        f32x4 acc[2] = {};
        #pragma unroll 8
        for (int ks = 0; ks < 32; ++ks) {
            int kc = (ks & 7) * 4 + q;
            int r2 = 4 * mi + (ks >> 3);
            bf16x8 a = *(const bf16x8*)(Ht + (r2 * 32 + (kc ^ (r2 & 31))) * 8);
            #pragma unroll
            for (int g = 0; g < 2; ++g) {
                bf16x8 bb = *(const bf16x8*)(w4c + ((size_t)((2 * w + g) * 32 + ks) * 64 + lane) * 8);
                acc[g] = __builtin_amdgcn_mfma_f32_16x16x32_bf16(a, bb, acc[g], 0, 0, 0);
            }
        }
        #pragma unroll
        for (int g = 0; g < 2; ++g) {
            int col = w * 32 + g * 16 + mi;
            float bv = b4[col];
            int chunk = col >> 3;
            #pragma unroll
            for (int i = 0; i < 4; ++i) {
                int row = q * 4 + i;
                Ht2[(row * 32 + (chunk ^ (row & 15))) * 8 + (col & 7)] =
                    __float2bfloat16(acc[g][i] + bv);
            }
        }
    }
    __syncthreads();

    // ---- phase C: 4 rows -> Ht3 (B coalesced from w4c) ----
    {
        f32x4 acc[2] = {};
        #pragma unroll 8
        for (int ks = 0; ks < 32; ++ks) {
            int kc = (ks & 7) * 4 + q;
            int r3 = (4 * mi + (ks >> 3)) & 15;
            bf16x8 a = *(const bf16x8*)(Ht2 + (r3 * 32 + (kc ^ (r3 & 15))) * 8);
            #pragma unroll
            for (int g = 0; g < 2; ++g) {
                bf16x8 bb = *(const bf16x8*)(w4c + ((size_t)((2 * w + g) * 32 + ks) * 64 + lane) * 8);
                acc[g] = __builtin_amdgcn_mfma_f32_16x16x32_bf16(a, bb, acc[g], 0, 0, 0);
            }
        }
        if (q == 0) {
            #pragma unroll
            for (int g = 0; g < 2; ++g) {
                int col = w * 32 + g * 16 + mi;
                float bv = b4[col];
                #pragma unroll
                for (int i = 0; i < 4; ++i)
                    Ht3[i * 256 + col] = __float2bfloat16(acc[g][i] + bv);
            }
        }
    }
    __syncthreads();

    // ---- phase D: 1 root -> out (B coalesced from w4c) ----
    {
        f32x4 acc[2] = {};
        #pragma unroll 8
        for (int ks = 0; ks < 32; ++ks) {
            int r4 = (4 * mi + (ks >> 3)) & 3;
            bf16x8 a = *(const bf16x8*)(Ht3 + r4 * 256 + (ks & 7) * 32 + q * 8);
            #pragma unroll
            for (int g = 0; g < 2; ++g) {
                bf16x8 bb = *(const bf16x8*)(w4c + ((size_t)((2 * w + g) * 32 + ks) * 64 + lane) * 8);
                acc[g] = __builtin_amdgcn_mfma_f32_16x16x32_bf16(a, bb, acc[g], 0, 0, 0);
            }
        }
        if (q == 0) {
            #pragma unroll
            for (int g = 0; g < 2; ++g) {
                int col = w * 32 + g * 16 + mi;
                out[(size_t)b * 256 + col] = acc[g][0] + b4[col];
            }
        }
    }
}

extern "C" void kernel_launch(void* const* d_in, const int* in_sizes, int n_in,
                              void* d_out, int out_size, void* d_ws, size_t ws_size,
                              hipStream_t stream) {
    const int*   ids = (const int*)d_in[0];
    const float* emb = (const float*)d_in[1];
    const float* W1  = (const float*)d_in[2];
    const float* b1  = (const float*)d_in[3];
    const float* W2  = (const float*)d_in[4];
    const float* b2  = (const float*)d_in[5];
    (void)in_sizes; (void)n_in; (void)out_size; (void)ws_size;

    char* ws = (char*)d_ws;
    size_t off = 0;
    float* zbuf = (float*)(ws + off); off += 1024;
    float* b4   = (float*)(ws + off); off += 1024;
    bf16* w1t = (bf16*)(ws + off); off += (size_t)256 * KP1 * 2;     // 160 KB
    bf16* w2t = (bf16*)(ws + off); off += (size_t)256 * 512 * 2;     // 256 KB
    bf16* w2b = (bf16*)(ws + off); off += (size_t)512 * 256 * 2;     // 256 KB
    bf16* w4t = (bf16*)(ws + off); off += (size_t)256 * 1024 * 2;    // 512 KB
    bf16* w4c = (bf16*)(ws + off); off += (size_t)256 * 1024 * 2;    // 512 KB
    bf16* proj = (bf16*)(ws + off); off += (size_t)MP * 256 * 2;     // 25.8 MB
    bf16* h  = (bf16*)(ws + off); off += (size_t)65536 * 256 * 2;    // 33.5 MB
    (void)off;

    // D1: weight casts/transposes + b4 + zeros
    prep_w<<<1345, 256, 0, stream>>>(W1, W2, b2, w1t, w2t, w2b, b4, zbuf);

    // D2: W4T (blocks 0..7) || proj (blocks 8..401)
    combo<<<402, 512, 0, stream>>>(emb, w1t, b1, w2t, w2b, w4t, proj, zbuf);

    // D3: coalesced-B permutation (tiny; feeds mainK + treeK phases B-D)
    w4cK<<<8, 512, 0, stream>>>(w4t, w4c);

    // D4: main — leaves + levels 0-1 (A-ring + register-B, counted vmcnt(10))
    mainK<<<512, 512, 0, stream>>>(proj, ids, w4c, b4, h);

    // D5: levels 2-10 block-local, 256 blocks (R6-verified)
    treeK<<<256, 512, 0, stream>>>(h, w4t, w4c, b4, (float*)d_out);
}